// Round 7
// baseline (641.932 us; speedup 1.0000x reference)
//
#include <hip/hip_runtime.h>
#include <hip/hip_bf16.h>

// Problem constants
#define NN 20000
#define NG 1250                  // node groups of 16, one per block
#define LOG2E 1.44269504088896f
#define TWOLOG2E 2.88539008177793f
#define SORT_BLOCKS 79           // 79*256 = 20224 >= 20000
#define PREP_BLOCKS 1024

typedef __attribute__((ext_vector_type(8))) short short8;   // 8 bf16 = 4 VGPRs (MFMA A/B frag)
typedef __attribute__((ext_vector_type(4))) float floatx4;  // MFMA C/D frag

__device__ __forceinline__ floatx4 MF(short8 a, short8 b, floatx4 c) {
    return __builtin_amdgcn_mfma_f32_16x16x32_bf16(a, b, c, 0, 0, 0);
}
__device__ __forceinline__ float ex2(float x) { return __builtin_amdgcn_exp2f(x); }
__device__ __forceinline__ float rcp(float x) { return __builtin_amdgcn_rcpf(x); }
__device__ __forceinline__ unsigned short bf16r(float x) {
    return __builtin_bit_cast(unsigned short, __float2bfloat16(x));
}
// barrier that waits ONLY lgkmcnt (LDS) — global prefetch stays in flight.
// The "memory" clobber also forces per-step re-loads of the Wih frags (they must NOT
// be hoisted into 32 persistent registers — that re-blows the (256,5) budget).
__device__ __forceinline__ void lds_barrier() {
    asm volatile("s_waitcnt lgkmcnt(0)\n\ts_barrier" ::: "memory");
}
// bank-conflict row swizzle for the h transpose tile (writer+reader must agree)
__device__ __forceinline__ int rowswz(int L) {
    return L ^ (((L >> 4) & 1) << 1) ^ ((L >> 3) & 1);
}

// ---------- fused prep + neighbor sort (one launch; sort latency hides under prep) ----------
#define PREP_TOT (49152 + 49152 + 12288 + 12288 + 768 + 640000)
__global__ void prep_sort_kernel(const float* __restrict__ x,
    const int* __restrict__ nbr, int* __restrict__ nbrT,
    const float* __restrict__ Wih0, const float* __restrict__ Whh0,
    const float* __restrict__ bih0, const float* __restrict__ bhh0, const float* __restrict__ Wl0,
    const float* __restrict__ Wih1, const float* __restrict__ Whh1,
    const float* __restrict__ bih1, const float* __restrict__ bhh1, const float* __restrict__ Wl1,
    const float* __restrict__ Wih2, const float* __restrict__ Whh2,
    const float* __restrict__ bih2, const float* __restrict__ bhh2, const float* __restrict__ Wl2,
    unsigned short* __restrict__ Wih_p, unsigned short* __restrict__ Whh_p,
    unsigned short* __restrict__ Wlx_p, unsigned short* __restrict__ Wlh_p,
    float* __restrict__ bsum, unsigned short* __restrict__ x32)
{
    if (blockIdx.x < SORT_BLOCKS) {
        // ---- sort each node's 32 neighbors ascending; store transposed per 16-node group ----
        int n = blockIdx.x * 256 + threadIdx.x;
        if (n >= NN) return;
        int v[32];
        const int4* src = (const int4*)(nbr + n * 32);
        #pragma unroll
        for (int i = 0; i < 8; i++) {
            int4 t = src[i];
            v[4*i] = t.x; v[4*i+1] = t.y; v[4*i+2] = t.z; v[4*i+3] = t.w;
        }
        #pragma unroll
        for (int k = 2; k <= 32; k <<= 1)
            #pragma unroll
            for (int j = k >> 1; j > 0; j >>= 1)
                #pragma unroll
                for (int i = 0; i < 32; i++) {
                    int ixj = i ^ j;
                    if (ixj > i) {
                        bool up = (i & k) == 0;
                        int a = v[i], b = v[ixj];
                        bool sw = up ? (a > b) : (a < b);
                        if (sw) { v[i] = b; v[ixj] = a; }
                    }
                }
        int g = n >> 4, m = n & 15;
        int base = g * 512 + m;      // nbrT[g][t][m]
        #pragma unroll
        for (int t = 0; t < 32; t++) nbrT[base + t * 16] = v[t];
        return;
    }

    // ---- prep: bf16 weight repack (log2e pre-folded), bias sums, padded x ----
    for (int i = (blockIdx.x - SORT_BLOCKS) * 256 + threadIdx.x; i < PREP_TOT;
         i += PREP_BLOCKS * 256) {
        int j = i;
        if (j < 49152) {                       // Wih_p: [col][k], layer0 K=32 padded from 3
            int l = j >> 14, e = j & 16383;
            if (l == 0) {
                if (e < 8192) {
                    int col = e >> 5, k = e & 31;
                    float sc = (col >= 128 && col < 192) ? TWOLOG2E : LOG2E;
                    float v = (k < 3) ? Wih0[col*3 + k] * sc : 0.f;
                    Wih_p[e] = bf16r(v);
                }
            } else {
                int col = e >> 6, k = e & 63;
                const float* W = (l == 1) ? Wih1 : Wih2;
                float sc = (col >= 128 && col < 192) ? TWOLOG2E : LOG2E;
                Wih_p[l*16384 + e] = bf16r(W[col*64 + k] * sc);
            }
            continue;
        }
        j -= 49152;
        if (j < 49152) {                       // Whh_p
            int l = j >> 14, e = j & 16383;
            int col = e >> 6, k = e & 63;
            const float* W = (l == 0) ? Whh0 : ((l == 1) ? Whh1 : Whh2);
            float sc = (col >= 128 && col < 192) ? TWOLOG2E : LOG2E;
            Whh_p[l*16384 + e] = bf16r(W[col*64 + k] * sc);
            continue;
        }
        j -= 49152;
        if (j < 12288) {                       // Wlx_p, layer0 K=32 padded from 3
            int l = j >> 12, e = j & 4095;
            if (l == 0) {
                if (e < 2048) {
                    int col = e >> 5, k = e & 31;
                    float v = (k < 3) ? Wl0[col*67 + k] : 0.f;
                    Wlx_p[e] = bf16r(v);
                }
            } else {
                int col = e >> 6, k = e & 63;
                const float* W = (l == 1) ? Wl1 : Wl2;
                Wlx_p[l*4096 + e] = bf16r(W[col*128 + k]);
            }
            continue;
        }
        j -= 12288;
        if (j < 12288) {                       // Wlh_p
            int l = j >> 12, e = j & 4095;
            int col = e >> 6, k = e & 63;
            float v = (l == 0) ? Wl0[col*67 + 3 + k]
                               : ((l == 1) ? Wl1 : Wl2)[col*128 + 64 + k];
            Wlh_p[l*4096 + e] = bf16r(v);
            continue;
        }
        j -= 12288;
        if (j < 768) {                         // bsum = (b_ih + b_hh) * scale
            int l = j >> 8, col = j & 255;
            const float* bi = (l == 0) ? bih0 : ((l == 1) ? bih1 : bih2);
            const float* bh = (l == 0) ? bhh0 : ((l == 1) ? bhh1 : bhh2);
            float sc = (col >= 128 && col < 192) ? TWOLOG2E : LOG2E;
            bsum[l*256 + col] = (bi[col] + bh[col]) * sc;
            continue;
        }
        j -= 768;
        {                                      // x32: padded bf16 node features [n][32]
            int n = j >> 5, k = j & 31;
            x32[j] = bf16r((k < 3) ? x[n*3 + k] : 0.f);
        }
    }
}

// ---------- fused LSTM-aggregate + combine (+head), MFMA version ----------
// R5 post-mortem: capacity was 4 blocks/CU (32KB sWih LDS tile) but the grid needs
// 4.88 -> two rounds, time-avg occupancy exactly the measured 31%. R6 proved the
// G-gather alternative thrashes L2 (248MB HBM fetch). This version keeps R5's
// x-MFMA structure but reads the Wih B-frags straight from GLOBAL (L2) each step:
// Wih_p is 64KB, read-only, shared by all 1250 blocks -> L2-hot; the per-step 4-8
// dwordx4 loads issue at step top and hide under the h-MFMA phase + TLP. The
// lds_barrier's memory clobber stops the compiler hoisting them into 32 persistent
// regs. LDS -> 4.4KB, live state ~90 regs -> __launch_bounds__(256,5): capacity 5,
// 1280 >= 1250, whole grid resident in ONE round (~19.5 waves/CU).
// Spill tripwire: WRITE_SIZE must stay 2500/2500/78 KB; VGPR <= ~102.
template<int XKC, int LASTL>
__global__ __launch_bounds__(256, 5)
void lstm_mfma_kernel(const unsigned short* __restrict__ xsrc,  // bf16 rows, stride XKC*32 shorts
                      const int* __restrict__ nbrT,
                      const unsigned short* __restrict__ Wih,   // bf16 [256][XKC*32]
                      const unsigned short* __restrict__ Whh,   // bf16 [256][64]
                      const float* __restrict__ bsum,           // [256] prescaled
                      const unsigned short* __restrict__ Wlx,   // bf16 [64][XKC*32]
                      const unsigned short* __restrict__ Wlh,   // bf16 [64][64]
                      const float* __restrict__ bl,             // [64]
                      const float* __restrict__ W_out,          // [64] (LASTL only)
                      const float* __restrict__ b_out,          // [1]  (LASTL only)
                      void* __restrict__ hout)                  // bf16[n][64] or float[n] (LASTL)
{
    __shared__ unsigned short sA[2][1024];   // h transpose, A-frag rows (swizzled), dbuf
    __shared__ float sRed[64];               // head partial sums (LASTL)

    const int w    = threadIdx.x >> 6;       // 0..3
    const int lane = threadIdx.x & 63;
    const int q    = lane >> 4;
    const int c    = lane & 15;
    const int XS   = XKC * 32;

    const int g = blockIdx.x;
    const int node0 = g * 16;
    const int* nbg = nbrT + g * 512;
    const int u = 16*w + c;

    // persistent h-weight fragments only: tile t4 = gate, col = 64*t4 + u
    short8 fWhh[4][2];
    float  biasv[4];
    #pragma unroll
    for (int t4 = 0; t4 < 4; t4++) {
        int col = 64*t4 + u;
        biasv[t4] = bsum[col];
        #pragma unroll
        for (int kc = 0; kc < 2; kc++)
            fWhh[t4][kc] = *(const short8*)(Whh + col*64 + kc*32 + q*8);
    }

    // per-step Wih B-frag: straight from global (L2-hot, 64KB shared by all blocks).
    // NOT cached in registers across steps (lds_barrier clobber forces re-load).
    auto loadWih = [&](int t4, int kc) -> short8 {
        int wcol = 64*t4 + u;
        return *(const short8*)(Wih + wcol*XS + kc*32 + q*8);
    };

    float cst[4] = {0.f, 0.f, 0.f, 0.f};
    short8 hA[2] = {};

    int idx_cur = nbg[c];
    int idx_nxt = nbg[16 + c];
    short8 xg[XKC];
    #pragma unroll
    for (int kc = 0; kc < XKC; kc++)
        xg[kc] = *(const short8*)(xsrc + (long)idx_cur * XS + kc*32 + q*8);

    #pragma unroll 1
    for (int t = 0; t < 32; t++) {
        floatx4 acc[4];
        #pragma unroll
        for (int t4 = 0; t4 < 4; t4++) {
            floatx4 a; a[0] = biasv[t4]; a[1] = biasv[t4]; a[2] = biasv[t4]; a[3] = biasv[t4];
            acc[t4] = a;
        }
        if (t > 0) {
            #pragma unroll
            for (int t4 = 0; t4 < 4; t4++) {
                acc[t4] = MF(hA[0], fWhh[t4][0], acc[t4]);
                acc[t4] = MF(hA[1], fWhh[t4][1], acc[t4]);
            }
        }
        #pragma unroll
        for (int t4 = 0; t4 < 4; t4++)
            #pragma unroll
            for (int kc = 0; kc < XKC; kc++)
                acc[t4] = MF(xg[kc], loadWih(t4, kc), acc[t4]);

        // prefetch next step's gathered rows (stays in flight across the lgkm-only barrier)
        if (t < 31) {
            #pragma unroll
            for (int kc = 0; kc < XKC; kc++)
                xg[kc] = *(const short8*)(xsrc + (long)idx_nxt * XS + kc*32 + q*8);
            int tn = (t + 2 < 32) ? t + 2 : 31;
            idx_nxt = nbg[tn*16 + c];
        }

        // pointwise LSTM cell; lane cells: node m=4q+r, unit u=16w+c (all 4 gates local)
        // 7 transcendentals/cell: one rcp(P*(1+ef)) serves sigm(f)=P*R and i*g's denom.
        unsigned short* sAb = sA[t & 1];
        #pragma unroll
        for (int r = 0; r < 4; r++) {
            float gi = acc[0][r], gf = acc[1][r], gg = acc[2][r], go = acc[3][r];
            float ei = ex2(-gi);
            float ef = ex2(-gf);
            float eo = ex2(-go);
            float eg = ex2(-__builtin_fabsf(gg));
            float P  = (1.f + ei) * (1.f + eg);
            float R  = rcp(P * (1.f + ef));
            float iG = __builtin_copysignf(1.f - eg, gg) * ((1.f + ef) * R);
            float cm = fmaf(cst[r], P * R, iG);             // P*R = sigm(gf)
            cst[r] = cm;
            float ec = ex2(-TWOLOG2E * __builtin_fabsf(cm));
            float h  = __builtin_copysignf(1.f - ec, cm) * rcp((1.f + eo) * (1.f + ec));
            int row = (4*q + r) + 16*(u >> 3);
            sAb[rowswz(row)*8 + (u & 7)] = bf16r(h);
        }
        lds_barrier();
        hA[0] = *(const short8*)(sA[t & 1] + rowswz(lane)*8);
        hA[1] = *(const short8*)(sA[t & 1] + 512 + rowswz(lane)*8);
    }

    // ---- combine: relu([h_in, agg] @ Wl^T + bl); agg frags = hA (final h) ----
    const int col = u;
    short8 fx[XKC], fh[2];
    float blv = bl[col];
    #pragma unroll
    for (int kc = 0; kc < XKC; kc++)
        fx[kc] = *(const short8*)(Wlx + col*XS + kc*32 + q*8);
    fh[0] = *(const short8*)(Wlh + col*64 + q*8);
    fh[1] = *(const short8*)(Wlh + col*64 + 32 + q*8);
    short8 hin[XKC];
    #pragma unroll
    for (int kc = 0; kc < XKC; kc++)
        hin[kc] = *(const short8*)(xsrc + (long)(node0 + c) * XS + kc*32 + q*8);

    floatx4 a; a[0] = blv; a[1] = blv; a[2] = blv; a[3] = blv;
    #pragma unroll
    for (int kc = 0; kc < XKC; kc++) a = MF(hin[kc], fx[kc], a);
    a = MF(hA[0], fh[0], a);
    a = MF(hA[1], fh[1], a);

    if (!LASTL) {
        #pragma unroll
        for (int r = 0; r < 4; r++)
            ((unsigned short*)hout)[(node0 + 4*q + r) * 64 + col] = bf16r(fmaxf(a[r], 0.f));
    } else {
        // fused head: out[n] = sum_u relu_comb[n][u] * W_out[u] + b_out
        float wo = W_out[col];
        float p[4];
        #pragma unroll
        for (int r = 0; r < 4; r++) p[r] = fmaxf(a[r], 0.f) * wo;
        #pragma unroll
        for (int d = 1; d < 16; d <<= 1) {
            #pragma unroll
            for (int r = 0; r < 4; r++) p[r] += __shfl_xor(p[r], d);
        }
        if (c == 0) {
            #pragma unroll
            for (int r = 0; r < 4; r++) sRed[w*16 + 4*q + r] = p[r];
        }
        lds_barrier();
        if (w == 0 && lane < 16)
            ((float*)hout)[node0 + lane] =
                sRed[lane] + sRed[16 + lane] + sRed[32 + lane] + sRed[48 + lane] + b_out[0];
    }
}

extern "C" void kernel_launch(void* const* d_in, const int* in_sizes, int n_in,
                              void* d_out, int out_size, void* d_ws, size_t ws_size,
                              hipStream_t stream) {
    (void)in_sizes; (void)n_in; (void)out_size; (void)ws_size;
    const float* node_features = (const float*)d_in[0];
    const int*   nbr           = (const int*)d_in[1];
    const float* Wih[3] = {(const float*)d_in[2],  (const float*)d_in[8],  (const float*)d_in[14]};
    const float* Whh[3] = {(const float*)d_in[3],  (const float*)d_in[9],  (const float*)d_in[15]};
    const float* bih[3] = {(const float*)d_in[4],  (const float*)d_in[10], (const float*)d_in[16]};
    const float* bhh[3] = {(const float*)d_in[5],  (const float*)d_in[11], (const float*)d_in[17]};
    const float* Wl[3]  = {(const float*)d_in[6],  (const float*)d_in[12], (const float*)d_in[18]};
    const float* bl[3]  = {(const float*)d_in[7],  (const float*)d_in[13], (const float*)d_in[19]};
    const float* W_out  = (const float*)d_in[20];
    const float* b_out  = (const float*)d_in[21];

    char* ws = (char*)d_ws;
    int*            nbrT  = (int*)ws;                               // 2,560,000 B
    unsigned short* x32   = (unsigned short*)(ws + 2560000);        // 1,280,000 B
    unsigned short* hb1   = (unsigned short*)(ws + 3840000);        // 2,560,000 B
    unsigned short* hb2   = (unsigned short*)(ws + 6400000);        // 2,560,000 B
    unsigned short* Wih_p = (unsigned short*)(ws + 8960000);        // 98,304 B
    unsigned short* Whh_p = (unsigned short*)(ws + 9058304);        // 98,304 B
    unsigned short* Wlx_p = (unsigned short*)(ws + 9156608);        // 24,576 B
    unsigned short* Wlh_p = (unsigned short*)(ws + 9181184);        // 24,576 B
    float*          bsum  = (float*)(ws + 9205760);                 // 3,072 B

    prep_sort_kernel<<<SORT_BLOCKS + PREP_BLOCKS, 256, 0, stream>>>(node_features,
        nbr, nbrT,
        Wih[0], Whh[0], bih[0], bhh[0], Wl[0],
        Wih[1], Whh[1], bih[1], bhh[1], Wl[1],
        Wih[2], Whh[2], bih[2], bhh[2], Wl[2],
        Wih_p, Whh_p, Wlx_p, Wlh_p, bsum, x32);

    lstm_mfma_kernel<1, 0><<<NG, 256, 0, stream>>>(x32, nbrT,
        Wih_p,         Whh_p,         bsum,       Wlx_p,        Wlh_p,        bl[0],
        nullptr, nullptr, hb1);
    lstm_mfma_kernel<2, 0><<<NG, 256, 0, stream>>>(hb1, nbrT,
        Wih_p + 16384, Whh_p + 16384, bsum + 256, Wlx_p + 4096, Wlh_p + 4096, bl[1],
        nullptr, nullptr, hb2);
    lstm_mfma_kernel<2, 1><<<NG, 256, 0, stream>>>(hb2, nbrT,
        Wih_p + 32768, Whh_p + 32768, bsum + 512, Wlx_p + 8192, Wlh_p + 8192, bl[2],
        W_out, b_out, (float*)d_out);
}

// Round 11
// 285.075 us; speedup vs baseline: 2.2518x; 2.2518x over previous
//
#include <hip/hip_runtime.h>
#include <hip/hip_bf16.h>

// Problem constants
#define NN 20000
#define NG 1250                  // node groups of 16, one per block (R5 geometry)
#define LOG2E 1.44269504088896f
#define TWOLOG2E 2.88539008177793f
#define SORT_BLOCKS 79           // 79*256 = 20224 >= 20000
#define PREP_BLOCKS 1024

typedef __attribute__((ext_vector_type(8))) short short8;   // 8 bf16 = 4 VGPRs (MFMA A/B frag)
typedef __attribute__((ext_vector_type(4))) float floatx4;  // MFMA C/D frag

__device__ __forceinline__ floatx4 MF(short8 a, short8 b, floatx4 c) {
    return __builtin_amdgcn_mfma_f32_16x16x32_bf16(a, b, c, 0, 0, 0);
}
__device__ __forceinline__ float ex2(float x) { return __builtin_amdgcn_exp2f(x); }
__device__ __forceinline__ float rcp(float x) { return __builtin_amdgcn_rcpf(x); }
__device__ __forceinline__ unsigned short bf16r(float x) {
    return __builtin_bit_cast(unsigned short, __float2bfloat16(x));
}
// barrier that waits ONLY lgkmcnt (LDS) — global prefetch stays in flight.
// The "memory" clobber also prevents the compiler from hoisting the per-step
// sWih LDS frag reads into persistent registers (which would re-blow the budget).
__device__ __forceinline__ void lds_barrier() {
    asm volatile("s_waitcnt lgkmcnt(0)\n\ts_barrier" ::: "memory");
}
// bank-conflict row swizzle for the h transpose tile (writer+reader must agree)
__device__ __forceinline__ int rowswz(int L) {
    return L ^ (((L >> 4) & 1) << 1) ^ ((L >> 3) & 1);
}

// ---------- fused prep + neighbor sort (one launch; sort latency hides under prep) ----------
#define PREP_TOT (49152 + 49152 + 12288 + 12288 + 768 + 640000)
__global__ void prep_sort_kernel(const float* __restrict__ x,
    const int* __restrict__ nbr, int* __restrict__ nbrT,
    const float* __restrict__ Wih0, const float* __restrict__ Whh0,
    const float* __restrict__ bih0, const float* __restrict__ bhh0, const float* __restrict__ Wl0,
    const float* __restrict__ Wih1, const float* __restrict__ Whh1,
    const float* __restrict__ bih1, const float* __restrict__ bhh1, const float* __restrict__ Wl1,
    const float* __restrict__ Wih2, const float* __restrict__ Whh2,
    const float* __restrict__ bih2, const float* __restrict__ bhh2, const float* __restrict__ Wl2,
    unsigned short* __restrict__ Wih_p, unsigned short* __restrict__ Whh_p,
    unsigned short* __restrict__ Wlx_p, unsigned short* __restrict__ Wlh_p,
    float* __restrict__ bsum, unsigned short* __restrict__ x32)
{
    if (blockIdx.x < SORT_BLOCKS) {
        // ---- sort each node's 32 neighbors ascending; store transposed per 16-node group ----
        int n = blockIdx.x * 256 + threadIdx.x;
        if (n >= NN) return;
        int v[32];
        const int4* src = (const int4*)(nbr + n * 32);
        #pragma unroll
        for (int i = 0; i < 8; i++) {
            int4 t = src[i];
            v[4*i] = t.x; v[4*i+1] = t.y; v[4*i+2] = t.z; v[4*i+3] = t.w;
        }
        #pragma unroll
        for (int k = 2; k <= 32; k <<= 1)
            #pragma unroll
            for (int j = k >> 1; j > 0; j >>= 1)
                #pragma unroll
                for (int i = 0; i < 32; i++) {
                    int ixj = i ^ j;
                    if (ixj > i) {
                        bool up = (i & k) == 0;
                        int a = v[i], b = v[ixj];
                        bool sw = up ? (a > b) : (a < b);
                        if (sw) { v[i] = b; v[ixj] = a; }
                    }
                }
        int g = n >> 4, m = n & 15;
        int base = g * 512 + m;      // nbrT[g][t][m]
        #pragma unroll
        for (int t = 0; t < 32; t++) nbrT[base + t * 16] = v[t];
        return;
    }

    // ---- prep: bf16 weight repack (log2e pre-folded), bias sums, padded x ----
    for (int i = (blockIdx.x - SORT_BLOCKS) * 256 + threadIdx.x; i < PREP_TOT;
         i += PREP_BLOCKS * 256) {
        int j = i;
        if (j < 49152) {                       // Wih_p: [col][k], layer0 K=32 padded from 3
            int l = j >> 14, e = j & 16383;
            if (l == 0) {
                if (e < 8192) {
                    int col = e >> 5, k = e & 31;
                    float sc = (col >= 128 && col < 192) ? TWOLOG2E : LOG2E;
                    float v = (k < 3) ? Wih0[col*3 + k] * sc : 0.f;
                    Wih_p[e] = bf16r(v);
                }
            } else {
                int col = e >> 6, k = e & 63;
                const float* W = (l == 1) ? Wih1 : Wih2;
                float sc = (col >= 128 && col < 192) ? TWOLOG2E : LOG2E;
                Wih_p[l*16384 + e] = bf16r(W[col*64 + k] * sc);
            }
            continue;
        }
        j -= 49152;
        if (j < 49152) {                       // Whh_p
            int l = j >> 14, e = j & 16383;
            int col = e >> 6, k = e & 63;
            const float* W = (l == 0) ? Whh0 : ((l == 1) ? Whh1 : Whh2);
            float sc = (col >= 128 && col < 192) ? TWOLOG2E : LOG2E;
            Whh_p[l*16384 + e] = bf16r(W[col*64 + k] * sc);
            continue;
        }
        j -= 49152;
        if (j < 12288) {                       // Wlx_p, layer0 K=32 padded from 3
            int l = j >> 12, e = j & 4095;
            if (l == 0) {
                if (e < 2048) {
                    int col = e >> 5, k = e & 31;
                    float v = (k < 3) ? Wl0[col*67 + k] : 0.f;
                    Wlx_p[e] = bf16r(v);
                }
            } else {
                int col = e >> 6, k = e & 63;
                const float* W = (l == 1) ? Wl1 : Wl2;
                Wlx_p[l*4096 + e] = bf16r(W[col*128 + k]);
            }
            continue;
        }
        j -= 12288;
        if (j < 12288) {                       // Wlh_p
            int l = j >> 12, e = j & 4095;
            int col = e >> 6, k = e & 63;
            float v = (l == 0) ? Wl0[col*67 + 3 + k]
                               : ((l == 1) ? Wl1 : Wl2)[col*128 + 64 + k];
            Wlh_p[l*4096 + e] = bf16r(v);
            continue;
        }
        j -= 12288;
        if (j < 768) {                         // bsum = (b_ih + b_hh) * scale
            int l = j >> 8, col = j & 255;
            const float* bi = (l == 0) ? bih0 : ((l == 1) ? bih1 : bih2);
            const float* bh = (l == 0) ? bhh0 : ((l == 1) ? bhh1 : bhh2);
            float sc = (col >= 128 && col < 192) ? TWOLOG2E : LOG2E;
            bsum[l*256 + col] = (bi[col] + bh[col]) * sc;
            continue;
        }
        j -= 768;
        {                                      // x32: padded bf16 node features [n][32]
            int n = j >> 5, k = j & 31;
            x32[j] = bf16r((k < 3) ? x[n*3 + k] : 0.f);
        }
    }
}

// ---------- fused LSTM-aggregate + combine (+head), MFMA version ----------
// R11 = R5 VERBATIM (harness-verified: 283.9us, absmax 1.953e-3). Session map:
//  - R1/R2 (2 groups/wave): -22% (killed grid-level slippage). R3 (acc ping-pong,
//    7-trans cell): neutral on its own; 7-trans kept here (verified in R5).
//  - R4 ((256,4) with reg-Wih): spills ~135>128. R5 fix: evict Wih to 32KB LDS tile.
//  - R6 (precomputed G gather): 248MB L2-thrash. R7 (per-step global W): 665MB. Never
//    re-read weights through the global path per step.
//  - R8/R9/R10 (512-thread 2-group; gate-split reg/LDS Wih): all fail correctness
//    nondeterministically (timed-run absmax 468); root cause never found by
//    inspection -> those restructures are RETIRED. Residency past 4 blocks/CU
//    remains theoretically ~1.3x but is unreachable without them.
// Occupancy model (verified): capacity = floor(160KB/37.4KB) = 4 blocks/CU; grid
// 1250 -> 2 rounds -> time-avg 9.75 waves/CU = measured 31%.
template<int XKC, int LASTL>
__global__ __launch_bounds__(256, 4)
void lstm_mfma_kernel(const unsigned short* __restrict__ xsrc,  // bf16 rows, stride XKC*32 shorts
                      const int* __restrict__ nbrT,
                      const unsigned short* __restrict__ Wih,   // bf16 [256][XKC*32]
                      const unsigned short* __restrict__ Whh,   // bf16 [256][64]
                      const float* __restrict__ bsum,           // [256] prescaled
                      const unsigned short* __restrict__ Wlx,   // bf16 [64][XKC*32]
                      const unsigned short* __restrict__ Wlh,   // bf16 [64][64]
                      const float* __restrict__ bl,             // [64]
                      const float* __restrict__ W_out,          // [64] (LASTL only)
                      const float* __restrict__ b_out,          // [1]  (LASTL only)
                      void* __restrict__ hout)                  // bf16[n][64] or float[n] (LASTL)
{
    __shared__ unsigned short sA[2][1024];   // h transpose, A-frag rows (swizzled), dbuf
    __shared__ float sRed[64];               // head partial sums (LASTL)
    __shared__ unsigned short sWih[(XKC == 2) ? 16384 : 64];  // [col][64shorts], swizzled

    const int w    = threadIdx.x >> 6;       // 0..3
    const int lane = threadIdx.x & 63;
    const int q    = lane >> 4;
    const int c    = lane & 15;
    const int XS   = XKC * 32;

    const int g = blockIdx.x;
    const int node0 = g * 16;
    const int* nbg = nbrT + g * 512;
    const int u = 16*w + c;

    // stage Wih tile into LDS (XKC==2): 2048 x 16B chunks, swizzled.
    // chunk (col, ch): global shorts col*64 + ch*8; LDS byte (col*128 + ch*16) ^ ((col&7)<<4)
    if constexpr (XKC == 2) {
        #pragma unroll
        for (int it = 0; it < 8; ++it) {
            int idx = it * 256 + threadIdx.x;       // 0..2047
            int col = idx >> 3, ch = idx & 7;
            short8 v = *(const short8*)(Wih + col*64 + ch*8);
            int wb = (col*128 + ch*16) ^ ((col & 7) << 4);
            *(short8*)((char*)sWih + wb) = v;
        }
    }

    // persistent weight fragments: tile t4 = gate, col = 64*t4 + u, k = 32kc+8q+j
    short8 fWhh[4][2];
    short8 fWih0[4];                     // XKC==1 only (16 regs)
    float  biasv[4];
    #pragma unroll
    for (int t4 = 0; t4 < 4; t4++) {
        int col = 64*t4 + u;
        biasv[t4] = bsum[col];
        #pragma unroll
        for (int kc = 0; kc < 2; kc++)
            fWhh[t4][kc] = *(const short8*)(Whh + col*64 + kc*32 + q*8);
        if constexpr (XKC == 1)
            fWih0[t4] = *(const short8*)(Wih + col*32 + q*8);
    }

    // per-step Wih B-frag: LDS read (XKC==2) or register (XKC==1)
    auto loadWih = [&](int t4, int kc) -> short8 {
        if constexpr (XKC == 2) {
            int wcol = 64*t4 + u;
            int wb = (wcol*128 + kc*64 + q*16) ^ ((wcol & 7) << 4);
            return *(const short8*)((const char*)sWih + wb);
        } else {
            (void)kc;
            return fWih0[t4];
        }
    };

    float cst[4] = {0.f, 0.f, 0.f, 0.f};
    short8 hA[2] = {};

    int idx_cur = nbg[c];
    int idx_nxt = nbg[16 + c];
    short8 xg[XKC];
    #pragma unroll
    for (int kc = 0; kc < XKC; kc++)
        xg[kc] = *(const short8*)(xsrc + (long)idx_cur * XS + kc*32 + q*8);

    if constexpr (XKC == 2) __syncthreads();   // sWih ready before first x-MFMA

    #pragma unroll 1
    for (int t = 0; t < 32; t++) {
        floatx4 acc[4];
        #pragma unroll
        for (int t4 = 0; t4 < 4; t4++) {
            floatx4 a; a[0] = biasv[t4]; a[1] = biasv[t4]; a[2] = biasv[t4]; a[3] = biasv[t4];
            acc[t4] = a;
        }
        if (t > 0) {
            #pragma unroll
            for (int t4 = 0; t4 < 4; t4++) {
                acc[t4] = MF(hA[0], fWhh[t4][0], acc[t4]);
                acc[t4] = MF(hA[1], fWhh[t4][1], acc[t4]);
            }
        }
        #pragma unroll
        for (int t4 = 0; t4 < 4; t4++)
            #pragma unroll
            for (int kc = 0; kc < XKC; kc++)
                acc[t4] = MF(xg[kc], loadWih(t4, kc), acc[t4]);

        // prefetch next step's gathered rows (stays in flight across the lgkm-only barrier)
        if (t < 31) {
            #pragma unroll
            for (int kc = 0; kc < XKC; kc++)
                xg[kc] = *(const short8*)(xsrc + (long)idx_nxt * XS + kc*32 + q*8);
            int tn = (t + 2 < 32) ? t + 2 : 31;
            idx_nxt = nbg[tn*16 + c];
        }

        // pointwise LSTM cell; lane cells: node m=4q+r, unit u=16w+c (all 4 gates local)
        // 7 transcendentals/cell: one rcp(P*(1+ef)) serves sigm(f)=P*R and i*g's denom.
        unsigned short* sAb = sA[t & 1];
        #pragma unroll
        for (int r = 0; r < 4; r++) {
            float gi = acc[0][r], gf = acc[1][r], gg = acc[2][r], go = acc[3][r];
            float ei = ex2(-gi);
            float ef = ex2(-gf);
            float eo = ex2(-go);
            float eg = ex2(-__builtin_fabsf(gg));
            float P  = (1.f + ei) * (1.f + eg);
            float R  = rcp(P * (1.f + ef));
            float iG = __builtin_copysignf(1.f - eg, gg) * ((1.f + ef) * R);
            float cm = fmaf(cst[r], P * R, iG);             // P*R = sigm(gf)
            cst[r] = cm;
            float ec = ex2(-TWOLOG2E * __builtin_fabsf(cm));
            float h  = __builtin_copysignf(1.f - ec, cm) * rcp((1.f + eo) * (1.f + ec));
            int row = (4*q + r) + 16*(u >> 3);
            sAb[rowswz(row)*8 + (u & 7)] = bf16r(h);
        }
        lds_barrier();
        hA[0] = *(const short8*)(sA[t & 1] + rowswz(lane)*8);
        hA[1] = *(const short8*)(sA[t & 1] + 512 + rowswz(lane)*8);
    }

    // ---- combine: relu([h_in, agg] @ Wl^T + bl); agg frags = hA (final h) ----
    const int col = u;
    short8 fx[XKC], fh[2];
    float blv = bl[col];
    #pragma unroll
    for (int kc = 0; kc < XKC; kc++)
        fx[kc] = *(const short8*)(Wlx + col*XS + kc*32 + q*8);
    fh[0] = *(const short8*)(Wlh + col*64 + q*8);
    fh[1] = *(const short8*)(Wlh + col*64 + 32 + q*8);
    short8 hin[XKC];
    #pragma unroll
    for (int kc = 0; kc < XKC; kc++)
        hin[kc] = *(const short8*)(xsrc + (long)(node0 + c) * XS + kc*32 + q*8);

    floatx4 a; a[0] = blv; a[1] = blv; a[2] = blv; a[3] = blv;
    #pragma unroll
    for (int kc = 0; kc < XKC; kc++) a = MF(hin[kc], fx[kc], a);
    a = MF(hA[0], fh[0], a);
    a = MF(hA[1], fh[1], a);

    if (!LASTL) {
        #pragma unroll
        for (int r = 0; r < 4; r++)
            ((unsigned short*)hout)[(node0 + 4*q + r) * 64 + col] = bf16r(fmaxf(a[r], 0.f));
    } else {
        // fused head: out[n] = sum_u relu_comb[n][u] * W_out[u] + b_out
        float wo = W_out[col];
        float p[4];
        #pragma unroll
        for (int r = 0; r < 4; r++) p[r] = fmaxf(a[r], 0.f) * wo;
        #pragma unroll
        for (int d = 1; d < 16; d <<= 1) {
            #pragma unroll
            for (int r = 0; r < 4; r++) p[r] += __shfl_xor(p[r], d);
        }
        if (c == 0) {
            #pragma unroll
            for (int r = 0; r < 4; r++) sRed[w*16 + 4*q + r] = p[r];
        }
        lds_barrier();
        if (w == 0 && lane < 16)
            ((float*)hout)[node0 + lane] =
                sRed[lane] + sRed[16 + lane] + sRed[32 + lane] + sRed[48 + lane] + b_out[0];
    }
}

extern "C" void kernel_launch(void* const* d_in, const int* in_sizes, int n_in,
                              void* d_out, int out_size, void* d_ws, size_t ws_size,
                              hipStream_t stream) {
    (void)in_sizes; (void)n_in; (void)out_size; (void)ws_size;
    const float* node_features = (const float*)d_in[0];
    const int*   nbr           = (const int*)d_in[1];
    const float* Wih[3] = {(const float*)d_in[2],  (const float*)d_in[8],  (const float*)d_in[14]};
    const float* Whh[3] = {(const float*)d_in[3],  (const float*)d_in[9],  (const float*)d_in[15]};
    const float* bih[3] = {(const float*)d_in[4],  (const float*)d_in[10], (const float*)d_in[16]};
    const float* bhh[3] = {(const float*)d_in[5],  (const float*)d_in[11], (const float*)d_in[17]};
    const float* Wl[3]  = {(const float*)d_in[6],  (const float*)d_in[12], (const float*)d_in[18]};
    const float* bl[3]  = {(const float*)d_in[7],  (const float*)d_in[13], (const float*)d_in[19]};
    const float* W_out  = (const float*)d_in[20];
    const float* b_out  = (const float*)d_in[21];

    char* ws = (char*)d_ws;
    int*            nbrT  = (int*)ws;                               // 2,560,000 B
    unsigned short* x32   = (unsigned short*)(ws + 2560000);        // 1,280,000 B
    unsigned short* hb1   = (unsigned short*)(ws + 3840000);        // 2,560,000 B
    unsigned short* hb2   = (unsigned short*)(ws + 6400000);        // 2,560,000 B
    unsigned short* Wih_p = (unsigned short*)(ws + 8960000);        // 98,304 B
    unsigned short* Whh_p = (unsigned short*)(ws + 9058304);        // 98,304 B
    unsigned short* Wlx_p = (unsigned short*)(ws + 9156608);        // 24,576 B
    unsigned short* Wlh_p = (unsigned short*)(ws + 9181184);        // 24,576 B
    float*          bsum  = (float*)(ws + 9205760);                 // 3,072 B

    prep_sort_kernel<<<SORT_BLOCKS + PREP_BLOCKS, 256, 0, stream>>>(node_features,
        nbr, nbrT,
        Wih[0], Whh[0], bih[0], bhh[0], Wl[0],
        Wih[1], Whh[1], bih[1], bhh[1], Wl[1],
        Wih[2], Whh[2], bih[2], bhh[2], Wl[2],
        Wih_p, Whh_p, Wlx_p, Wlh_p, bsum, x32);

    lstm_mfma_kernel<1, 0><<<NG, 256, 0, stream>>>(x32, nbrT,
        Wih_p,         Whh_p,         bsum,       Wlx_p,        Wlh_p,        bl[0],
        nullptr, nullptr, hb1);
    lstm_mfma_kernel<2, 0><<<NG, 256, 0, stream>>>(hb1, nbrT,
        Wih_p + 16384, Whh_p + 16384, bsum + 256, Wlx_p + 4096, Wlh_p + 4096, bl[1],
        nullptr, nullptr, hb2);
    lstm_mfma_kernel<2, 1><<<NG, 256, 0, stream>>>(hb2, nbrT,
        Wih_p + 32768, Whh_p + 32768, bsum + 512, Wlx_p + 8192, Wlh_p + 8192, bl[2],
        W_out, b_out, (float*)d_out);
}

// Round 12
// 283.907 us; speedup vs baseline: 2.2611x; 1.0041x over previous
//
#include <hip/hip_runtime.h>
#include <hip/hip_bf16.h>

// Problem constants
#define NN 20000
#define NG 1250                  // node groups of 16, one per block (R5 geometry)
#define LOG2E 1.44269504088896f
#define TWOLOG2E 2.88539008177793f
#define SORT_BLOCKS 79           // 79*256 = 20224 >= 20000
#define PREP_BLOCKS 1024

typedef __attribute__((ext_vector_type(8))) short short8;   // 8 bf16 = 4 VGPRs (MFMA A/B frag)
typedef __attribute__((ext_vector_type(4))) float floatx4;  // MFMA C/D frag
typedef __attribute__((ext_vector_type(4))) unsigned short ushortx4;

__device__ __forceinline__ floatx4 MF(short8 a, short8 b, floatx4 c) {
    return __builtin_amdgcn_mfma_f32_16x16x32_bf16(a, b, c, 0, 0, 0);
}
__device__ __forceinline__ float ex2(float x) { return __builtin_amdgcn_exp2f(x); }
__device__ __forceinline__ float rcp(float x) { return __builtin_amdgcn_rcpf(x); }
__device__ __forceinline__ unsigned short bf16r(float x) {
    return __builtin_bit_cast(unsigned short, __float2bfloat16(x));
}
// barrier that waits ONLY lgkmcnt (LDS) — global prefetch stays in flight.
// The "memory" clobber also prevents the compiler from hoisting the per-step
// sWih LDS frag reads into persistent registers (which would re-blow the budget).
__device__ __forceinline__ void lds_barrier() {
    asm volatile("s_waitcnt lgkmcnt(0)\n\ts_barrier" ::: "memory");
}
// bank-conflict row swizzle for the h transpose tile (writer+reader must agree)
__device__ __forceinline__ int rowswz(int L) {
    return L ^ (((L >> 4) & 1) << 1) ^ ((L >> 3) & 1);
}

// ---------- fused prep + neighbor sort (one launch; sort latency hides under prep) ----------
// x32 section vectorized: 160000 short4 chunks instead of 640000 scalar shorts.
#define PREP_TOT (49152 + 49152 + 12288 + 12288 + 768 + 160000)
__global__ void prep_sort_kernel(const float* __restrict__ x,
    const int* __restrict__ nbr, int* __restrict__ nbrT,
    const float* __restrict__ Wih0, const float* __restrict__ Whh0,
    const float* __restrict__ bih0, const float* __restrict__ bhh0, const float* __restrict__ Wl0,
    const float* __restrict__ Wih1, const float* __restrict__ Whh1,
    const float* __restrict__ bih1, const float* __restrict__ bhh1, const float* __restrict__ Wl1,
    const float* __restrict__ Wih2, const float* __restrict__ Whh2,
    const float* __restrict__ bih2, const float* __restrict__ bhh2, const float* __restrict__ Wl2,
    unsigned short* __restrict__ Wih_p, unsigned short* __restrict__ Whh_p,
    unsigned short* __restrict__ Wlx_p, unsigned short* __restrict__ Wlh_p,
    float* __restrict__ bsum, unsigned short* __restrict__ x32)
{
    if (blockIdx.x < SORT_BLOCKS) {
        // ---- sort each node's 32 neighbors ascending; store transposed per 16-node group ----
        int n = blockIdx.x * 256 + threadIdx.x;
        if (n >= NN) return;
        int v[32];
        const int4* src = (const int4*)(nbr + n * 32);
        #pragma unroll
        for (int i = 0; i < 8; i++) {
            int4 t = src[i];
            v[4*i] = t.x; v[4*i+1] = t.y; v[4*i+2] = t.z; v[4*i+3] = t.w;
        }
        #pragma unroll
        for (int k = 2; k <= 32; k <<= 1)
            #pragma unroll
            for (int j = k >> 1; j > 0; j >>= 1)
                #pragma unroll
                for (int i = 0; i < 32; i++) {
                    int ixj = i ^ j;
                    if (ixj > i) {
                        bool up = (i & k) == 0;
                        int a = v[i], b = v[ixj];
                        bool sw = up ? (a > b) : (a < b);
                        if (sw) { v[i] = b; v[ixj] = a; }
                    }
                }
        int g = n >> 4, m = n & 15;
        int base = g * 512 + m;      // nbrT[g][t][m]
        #pragma unroll
        for (int t = 0; t < 32; t++) nbrT[base + t * 16] = v[t];
        return;
    }

    // ---- prep: bf16 weight repack (log2e pre-folded), bias sums, padded x ----
    for (int i = (blockIdx.x - SORT_BLOCKS) * 256 + threadIdx.x; i < PREP_TOT;
         i += PREP_BLOCKS * 256) {
        int j = i;
        if (j < 49152) {                       // Wih_p: [col][k], layer0 K=32 padded from 3
            int l = j >> 14, e = j & 16383;
            if (l == 0) {
                if (e < 8192) {
                    int col = e >> 5, k = e & 31;
                    float sc = (col >= 128 && col < 192) ? TWOLOG2E : LOG2E;
                    float v = (k < 3) ? Wih0[col*3 + k] * sc : 0.f;
                    Wih_p[e] = bf16r(v);
                }
            } else {
                int col = e >> 6, k = e & 63;
                const float* W = (l == 1) ? Wih1 : Wih2;
                float sc = (col >= 128 && col < 192) ? TWOLOG2E : LOG2E;
                Wih_p[l*16384 + e] = bf16r(W[col*64 + k] * sc);
            }
            continue;
        }
        j -= 49152;
        if (j < 49152) {                       // Whh_p
            int l = j >> 14, e = j & 16383;
            int col = e >> 6, k = e & 63;
            const float* W = (l == 0) ? Whh0 : ((l == 1) ? Whh1 : Whh2);
            float sc = (col >= 128 && col < 192) ? TWOLOG2E : LOG2E;
            Whh_p[l*16384 + e] = bf16r(W[col*64 + k] * sc);
            continue;
        }
        j -= 49152;
        if (j < 12288) {                       // Wlx_p, layer0 K=32 padded from 3
            int l = j >> 12, e = j & 4095;
            if (l == 0) {
                if (e < 2048) {
                    int col = e >> 5, k = e & 31;
                    float v = (k < 3) ? Wl0[col*67 + k] : 0.f;
                    Wlx_p[e] = bf16r(v);
                }
            } else {
                int col = e >> 6, k = e & 63;
                const float* W = (l == 1) ? Wl1 : Wl2;
                Wlx_p[l*4096 + e] = bf16r(W[col*128 + k]);
            }
            continue;
        }
        j -= 12288;
        if (j < 12288) {                       // Wlh_p
            int l = j >> 12, e = j & 4095;
            int col = e >> 6, k = e & 63;
            float v = (l == 0) ? Wl0[col*67 + 3 + k]
                               : ((l == 1) ? Wl1 : Wl2)[col*128 + 64 + k];
            Wlh_p[l*4096 + e] = bf16r(v);
            continue;
        }
        j -= 12288;
        if (j < 768) {                         // bsum = (b_ih + b_hh) * scale
            int l = j >> 8, col = j & 255;
            const float* bi = (l == 0) ? bih0 : ((l == 1) ? bih1 : bih2);
            const float* bh = (l == 0) ? bhh0 : ((l == 1) ? bhh1 : bhh2);
            float sc = (col >= 128 && col < 192) ? TWOLOG2E : LOG2E;
            bsum[l*256 + col] = (bi[col] + bh[col]) * sc;
            continue;
        }
        j -= 768;
        {                                      // x32: padded bf16 node features [n][32], short4
            int n = j >> 3, kb = (j & 7) * 4;  // chunk j -> shorts 4j..4j+3
            ushortx4 v = {0, 0, 0, 0};
            if (kb == 0) {
                v[0] = bf16r(x[n*3]);
                v[1] = bf16r(x[n*3 + 1]);
                v[2] = bf16r(x[n*3 + 2]);
            }
            *(ushortx4*)(x32 + 4*j) = v;
        }
    }
}

// ---------- fused LSTM-aggregate + combine (+head), MFMA version ----------
// R12 = R11 (harness-verified 285.1us) + three provably-safe micro-deltas:
//  (a) s_setprio(1) around the MFMA cluster (T5): 4 barrier-independent blocks/CU
//      give phase diversity; MFMA-phase waves get scheduler preference over
//      pointwise-phase waves. Pure hint, no correctness surface.
//  (b) gate-0 Wih frags cached in 8 spare VGPRs (fWihC): 2 fewer ds_reads/step.
//      NOT the retired R10 split: the 32KB LDS tile, staging, (256,4) bounds and
//      capacity are byte-identical; one read is redirected to a register copy.
//  (c) vectorized x32 prep (short4 stores).
// Session map: R1/R2 2-groups/wave -22%; R4 (256,4)+reg-Wih spills; R6 gather-G
// 248MB L2-thrash; R7 per-step global-W 665MB; R8/R9/R10 capacity-5 restructures
// fail correctness nondeterministically -> RETIRED. Occupancy model (verified):
// capacity = floor(160KB/37.4KB) = 4 blocks/CU; grid 1250 -> 2 rounds -> time-avg
// 9.75 waves/CU = measured 31%.
template<int XKC, int LASTL>
__global__ __launch_bounds__(256, 4)
void lstm_mfma_kernel(const unsigned short* __restrict__ xsrc,  // bf16 rows, stride XKC*32 shorts
                      const int* __restrict__ nbrT,
                      const unsigned short* __restrict__ Wih,   // bf16 [256][XKC*32]
                      const unsigned short* __restrict__ Whh,   // bf16 [256][64]
                      const float* __restrict__ bsum,           // [256] prescaled
                      const unsigned short* __restrict__ Wlx,   // bf16 [64][XKC*32]
                      const unsigned short* __restrict__ Wlh,   // bf16 [64][64]
                      const float* __restrict__ bl,             // [64]
                      const float* __restrict__ W_out,          // [64] (LASTL only)
                      const float* __restrict__ b_out,          // [1]  (LASTL only)
                      void* __restrict__ hout)                  // bf16[n][64] or float[n] (LASTL)
{
    __shared__ unsigned short sA[2][1024];   // h transpose, A-frag rows (swizzled), dbuf
    __shared__ float sRed[64];               // head partial sums (LASTL)
    __shared__ unsigned short sWih[(XKC == 2) ? 16384 : 64];  // [col][64shorts], swizzled

    const int w    = threadIdx.x >> 6;       // 0..3
    const int lane = threadIdx.x & 63;
    const int q    = lane >> 4;
    const int c    = lane & 15;
    const int XS   = XKC * 32;

    const int g = blockIdx.x;
    const int node0 = g * 16;
    const int* nbg = nbrT + g * 512;
    const int u = 16*w + c;

    // stage Wih tile into LDS (XKC==2): 2048 x 16B chunks, swizzled.
    // chunk (col, ch): global shorts col*64 + ch*8; LDS byte (col*128 + ch*16) ^ ((col&7)<<4)
    if constexpr (XKC == 2) {
        #pragma unroll
        for (int it = 0; it < 8; ++it) {
            int idx = it * 256 + threadIdx.x;       // 0..2047
            int col = idx >> 3, ch = idx & 7;
            short8 v = *(const short8*)(Wih + col*64 + ch*8);
            int wb = (col*128 + ch*16) ^ ((col & 7) << 4);
            *(short8*)((char*)sWih + wb) = v;
        }
    }

    // persistent weight fragments: tile t4 = gate, col = 64*t4 + u, k = 32kc+8q+j
    short8 fWhh[4][2];
    short8 fWih0[4];                     // XKC==1 only (16 regs)
    short8 fWihC[2];                     // XKC==2: gate-0 chunks cached in regs (8 regs)
    float  biasv[4];
    #pragma unroll
    for (int t4 = 0; t4 < 4; t4++) {
        int col = 64*t4 + u;
        biasv[t4] = bsum[col];
        #pragma unroll
        for (int kc = 0; kc < 2; kc++)
            fWhh[t4][kc] = *(const short8*)(Whh + col*64 + kc*32 + q*8);
        if constexpr (XKC == 1)
            fWih0[t4] = *(const short8*)(Wih + col*32 + q*8);
    }
    if constexpr (XKC == 2) {
        #pragma unroll
        for (int kc = 0; kc < 2; kc++)
            fWihC[kc] = *(const short8*)(Wih + u*XS + kc*32 + q*8);   // col = u (gate 0)
    }

    // per-step Wih B-frag: reg cache (gate 0), LDS (gates 1-3, XKC==2), reg (XKC==1)
    auto loadWih = [&](int t4, int kc) -> short8 {
        if constexpr (XKC == 2) {
            if (t4 == 0) return fWihC[kc];
            int wcol = 64*t4 + u;
            int wb = (wcol*128 + kc*64 + q*16) ^ ((wcol & 7) << 4);
            return *(const short8*)((const char*)sWih + wb);
        } else {
            (void)kc;
            return fWih0[t4];
        }
    };

    float cst[4] = {0.f, 0.f, 0.f, 0.f};
    short8 hA[2] = {};

    int idx_cur = nbg[c];
    int idx_nxt = nbg[16 + c];
    short8 xg[XKC];
    #pragma unroll
    for (int kc = 0; kc < XKC; kc++)
        xg[kc] = *(const short8*)(xsrc + (long)idx_cur * XS + kc*32 + q*8);

    if constexpr (XKC == 2) __syncthreads();   // sWih ready before first x-MFMA

    #pragma unroll 1
    for (int t = 0; t < 32; t++) {
        floatx4 acc[4];
        #pragma unroll
        for (int t4 = 0; t4 < 4; t4++) {
            floatx4 a; a[0] = biasv[t4]; a[1] = biasv[t4]; a[2] = biasv[t4]; a[3] = biasv[t4];
            acc[t4] = a;
        }
        __builtin_amdgcn_s_setprio(1);           // favor MFMA-phase waves (T5)
        if (t > 0) {
            #pragma unroll
            for (int t4 = 0; t4 < 4; t4++) {
                acc[t4] = MF(hA[0], fWhh[t4][0], acc[t4]);
                acc[t4] = MF(hA[1], fWhh[t4][1], acc[t4]);
            }
        }
        #pragma unroll
        for (int t4 = 0; t4 < 4; t4++)
            #pragma unroll
            for (int kc = 0; kc < XKC; kc++)
                acc[t4] = MF(xg[kc], loadWih(t4, kc), acc[t4]);
        __builtin_amdgcn_s_setprio(0);

        // prefetch next step's gathered rows (stays in flight across the lgkm-only barrier)
        if (t < 31) {
            #pragma unroll
            for (int kc = 0; kc < XKC; kc++)
                xg[kc] = *(const short8*)(xsrc + (long)idx_nxt * XS + kc*32 + q*8);
            int tn = (t + 2 < 32) ? t + 2 : 31;
            idx_nxt = nbg[tn*16 + c];
        }

        // pointwise LSTM cell; lane cells: node m=4q+r, unit u=16w+c (all 4 gates local)
        // 7 transcendentals/cell: one rcp(P*(1+ef)) serves sigm(f)=P*R and i*g's denom.
        unsigned short* sAb = sA[t & 1];
        #pragma unroll
        for (int r = 0; r < 4; r++) {
            float gi = acc[0][r], gf = acc[1][r], gg = acc[2][r], go = acc[3][r];
            float ei = ex2(-gi);
            float ef = ex2(-gf);
            float eo = ex2(-go);
            float eg = ex2(-__builtin_fabsf(gg));
            float P  = (1.f + ei) * (1.f + eg);
            float R  = rcp(P * (1.f + ef));
            float iG = __builtin_copysignf(1.f - eg, gg) * ((1.f + ef) * R);
            float cm = fmaf(cst[r], P * R, iG);             // P*R = sigm(gf)
            cst[r] = cm;
            float ec = ex2(-TWOLOG2E * __builtin_fabsf(cm));
            float h  = __builtin_copysignf(1.f - ec, cm) * rcp((1.f + eo) * (1.f + ec));
            int row = (4*q + r) + 16*(u >> 3);
            sAb[rowswz(row)*8 + (u & 7)] = bf16r(h);
        }
        lds_barrier();
        hA[0] = *(const short8*)(sA[t & 1] + rowswz(lane)*8);
        hA[1] = *(const short8*)(sA[t & 1] + 512 + rowswz(lane)*8);
    }

    // ---- combine: relu([h_in, agg] @ Wl^T + bl); agg frags = hA (final h) ----
    const int col = u;
    short8 fx[XKC], fh[2];
    float blv = bl[col];
    #pragma unroll
    for (int kc = 0; kc < XKC; kc++)
        fx[kc] = *(const short8*)(Wlx + col*XS + kc*32 + q*8);
    fh[0] = *(const short8*)(Wlh + col*64 + q*8);
    fh[1] = *(const short8*)(Wlh + col*64 + 32 + q*8);
    short8 hin[XKC];
    #pragma unroll
    for (int kc = 0; kc < XKC; kc++)
        hin[kc] = *(const short8*)(xsrc + (long)(node0 + c) * XS + kc*32 + q*8);

    floatx4 a; a[0] = blv; a[1] = blv; a[2] = blv; a[3] = blv;
    #pragma unroll
    for (int kc = 0; kc < XKC; kc++) a = MF(hin[kc], fx[kc], a);
    a = MF(hA[0], fh[0], a);
    a = MF(hA[1], fh[1], a);

    if (!LASTL) {
        #pragma unroll
        for (int r = 0; r < 4; r++)
            ((unsigned short*)hout)[(node0 + 4*q + r) * 64 + col] = bf16r(fmaxf(a[r], 0.f));
    } else {
        // fused head: out[n] = sum_u relu_comb[n][u] * W_out[u] + b_out
        float wo = W_out[col];
        float p[4];
        #pragma unroll
        for (int r = 0; r < 4; r++) p[r] = fmaxf(a[r], 0.f) * wo;
        #pragma unroll
        for (int d = 1; d < 16; d <<= 1) {
            #pragma unroll
            for (int r = 0; r < 4; r++) p[r] += __shfl_xor(p[r], d);
        }
        if (c == 0) {
            #pragma unroll
            for (int r = 0; r < 4; r++) sRed[w*16 + 4*q + r] = p[r];
        }
        lds_barrier();
        if (w == 0 && lane < 16)
            ((float*)hout)[node0 + lane] =
                sRed[lane] + sRed[16 + lane] + sRed[32 + lane] + sRed[48 + lane] + b_out[0];
    }
}

extern "C" void kernel_launch(void* const* d_in, const int* in_sizes, int n_in,
                              void* d_out, int out_size, void* d_ws, size_t ws_size,
                              hipStream_t stream) {
    (void)in_sizes; (void)n_in; (void)out_size; (void)ws_size;
    const float* node_features = (const float*)d_in[0];
    const int*   nbr           = (const int*)d_in[1];
    const float* Wih[3] = {(const float*)d_in[2],  (const float*)d_in[8],  (const float*)d_in[14]};
    const float* Whh[3] = {(const float*)d_in[3],  (const float*)d_in[9],  (const float*)d_in[15]};
    const float* bih[3] = {(const float*)d_in[4],  (const float*)d_in[10], (const float*)d_in[16]};
    const float* bhh[3] = {(const float*)d_in[5],  (const float*)d_in[11], (const float*)d_in[17]};
    const float* Wl[3]  = {(const float*)d_in[6],  (const float*)d_in[12], (const float*)d_in[18]};
    const float* bl[3]  = {(const float*)d_in[7],  (const float*)d_in[13], (const float*)d_in[19]};
    const float* W_out  = (const float*)d_in[20];
    const float* b_out  = (const float*)d_in[21];

    char* ws = (char*)d_ws;
    int*            nbrT  = (int*)ws;                               // 2,560,000 B
    unsigned short* x32   = (unsigned short*)(ws + 2560000);        // 1,280,000 B
    unsigned short* hb1   = (unsigned short*)(ws + 3840000);        // 2,560,000 B
    unsigned short* hb2   = (unsigned short*)(ws + 6400000);        // 2,560,000 B
    unsigned short* Wih_p = (unsigned short*)(ws + 8960000);        // 98,304 B
    unsigned short* Whh_p = (unsigned short*)(ws + 9058304);        // 98,304 B
    unsigned short* Wlx_p = (unsigned short*)(ws + 9156608);        // 24,576 B
    unsigned short* Wlh_p = (unsigned short*)(ws + 9181184);        // 24,576 B
    float*          bsum  = (float*)(ws + 9205760);                 // 3,072 B

    prep_sort_kernel<<<SORT_BLOCKS + PREP_BLOCKS, 256, 0, stream>>>(node_features,
        nbr, nbrT,
        Wih[0], Whh[0], bih[0], bhh[0], Wl[0],
        Wih[1], Whh[1], bih[1], bhh[1], Wl[1],
        Wih[2], Whh[2], bih[2], bhh[2], Wl[2],
        Wih_p, Whh_p, Wlx_p, Wlh_p, bsum, x32);

    lstm_mfma_kernel<1, 0><<<NG, 256, 0, stream>>>(x32, nbrT,
        Wih_p,         Whh_p,         bsum,       Wlx_p,        Wlh_p,        bl[0],
        nullptr, nullptr, hb1);
    lstm_mfma_kernel<2, 0><<<NG, 256, 0, stream>>>(hb1, nbrT,
        Wih_p + 16384, Whh_p + 16384, bsum + 256, Wlx_p + 4096, Wlh_p + 4096, bl[1],
        nullptr, nullptr, hb2);
    lstm_mfma_kernel<2, 1><<<NG, 256, 0, stream>>>(hb2, nbrT,
        Wih_p + 32768, Whh_p + 32768, bsum + 512, Wlx_p + 8192, Wlh_p + 8192, bl[2],
        W_out, b_out, (float*)d_out);
}